// Round 5
// baseline (129.826 us; speedup 1.0000x reference)
//
#include <hip/hip_runtime.h>
#include <stdint.h>

// BinarizedConv2d: out[d,h,w,o] = 1152 - 2*popcount(x_patch XOR w_filter)
// Per (tap,c) bit pair: 4xw - 2x - 2w + 1 == 1 - 2*(x^w); zero-padded x
// contributes 1-2w, matching the reference. Exact integers in fp32.
//
// Two dispatches (cooperative launch unusable - R3; monolithic fusion is
// latency-bound at 1 block/CU - R4):
//   1) pack_kernel: 9344 blocks - blocks [0,8192) bit-pack x via ballot,
//      blocks [8192,9344) bit-pack w. Pure streaming, high occupancy.
//   2) binconv: 512 blocks x 256 thr, 2 output rows/thread (halves LDS
//      reads/output), reads packed data (LLC-hot), writes out.
// Bit permutation (same in both pack paths; popcount is order-agnostic):
// word k (k=0..3), bit j (j=0..31) <-> channel 4j+k.

#define D_    64
#define H_    32
#define W_    32
#define CIN_  128
#define COUT_ 128
#define KK_   1152   // CIN * 3 * 3

#define XBLOCKS 8192   // x-pack: 65536 pos * 32 chunks / 256 thr
#define WBLOCKS 1152   // w-pack: 576 (d,tap) * 4 k * 128 o / 256 thr

// ---------------------------------------------------------------------------
// Pack kernel (single dispatch, block-range split; branch is block-uniform).
// ---------------------------------------------------------------------------
__global__ __launch_bounds__(256) void pack_kernel(const int* __restrict__ x,
                                                   const float* __restrict__ w,
                                                   uint4* __restrict__ xb,
                                                   unsigned* __restrict__ wbw) {
    int b = blockIdx.x;
    if (b < XBLOCKS) {
        // ---- pack x: thread = (pos, c4); int4 load = channels 4c4..4c4+3.
        // Lanes 0-31 -> pos, lanes 32-63 -> pos+1; half-wave leaders store.
        int gid = b * 256 + threadIdx.x;
        int pos = gid >> 5;
        int c4  = gid & 31;
        int4 v = ((const int4*)(x + (long)pos * CIN_))[c4];
        unsigned long long b0 = __ballot(v.x != 0);
        unsigned long long b1 = __ballot(v.y != 0);
        unsigned long long b2 = __ballot(v.z != 0);
        unsigned long long b3 = __ballot(v.w != 0);
        int lane = threadIdx.x & 63;
        if (lane == 0)
            xb[pos] = make_uint4((unsigned)b0, (unsigned)b1,
                                 (unsigned)b2, (unsigned)b3);
        else if (lane == 32)
            xb[pos] = make_uint4((unsigned)(b0 >> 32), (unsigned)(b1 >> 32),
                                 (unsigned)(b2 >> 32), (unsigned)(b3 >> 32));
    } else {
        // ---- pack w: thread = (dt, k, o); 32 coalesced strided loads.
        int t    = (b - XBLOCKS) * 256 + threadIdx.x;
        int o    = t & 127;
        int rest = t >> 7;
        int k    = rest & 3;
        int dt   = rest >> 2;          // d*9 + tap
        int d    = dt / 9;
        int tap  = dt - d * 9;
        const float* wp = w + (long)dt * (CIN_ * COUT_) + o;
        unsigned m = 0;
#pragma unroll
        for (int j = 0; j < 32; ++j)
            if (wp[(long)(4 * j + k) * COUT_] != 0.f) m |= 1u << j;
        wbw[(((long)d * COUT_ + o) * 9 + tap) * 4 + k] = m;
    }
}

// ---------------------------------------------------------------------------
// Conv kernel. Block = (d = bid&63, tile = bid>>6): rows h0..h0+3, h0=tile*4.
// Thread = (o = tid&127, rp = tid>>7): output rows h0+2rp, h0+2rp+1.
// x tile (6 rows x 34 halo cols) in LDS; reads are wave-uniform (broadcast).
// Sliding 4-row x 3-col register window: 4 ds_read_b128 per 2 outputs.
// d in low bits of bid => same-d blocks 64 apart => same XCD => xb/wb L2 hits.
// ---------------------------------------------------------------------------
__global__ __launch_bounds__(256) void binconv_kernel(const uint4* __restrict__ xb,
                                                      const uint4* __restrict__ wb,
                                                      float* __restrict__ out) {
    __shared__ uint4 xbt[6][34];

    int bid  = blockIdx.x;
    int d    = bid & 63;
    int tile = bid >> 6;           // 0..7
    int h0   = tile * 4;
    int tid  = threadIdx.x;
    int o    = tid & 127;
    int rp   = tid >> 7;           // 0 or 1 (wave-uniform)

    // Stage x tile: rows h0-1 .. h0+4, cols -1 .. 32 (zeros at boundaries).
    if (tid < 6 * 34) {
        int r  = tid / 34;
        int cc = tid - r * 34;
        int hh = h0 - 1 + r;
        int ww = cc - 1;
        uint4 v = make_uint4(0u, 0u, 0u, 0u);
        if (hh >= 0 && hh < H_ && ww >= 0 && ww < W_)
            v = xb[(long)d * (H_ * W_) + hh * W_ + ww];
        xbt[r][cc] = v;
    }

    // Weights for this (d, o): 9 taps x 16B, resident in VGPRs (LLC-hot).
    uint4 wv[9];
    const uint4* wp = wb + (long)(d * COUT_ + o) * 9;
#pragma unroll
    for (int t = 0; t < 9; ++t) wv[t] = wp[t];

    __syncthreads();

    int r0 = 2 * rp;               // window base row within the LDS tile
    int h  = h0 + 2 * rp;
    float* op0 = out + ((long)d * (H_ * W_) + h * W_) * COUT_ + o;
    float* op1 = op0 + (long)W_ * COUT_;

    // Sliding window: 4 tile-rows x 3 columns in registers.
    uint4 ca[4], cb[4], cc_[4];
#pragma unroll
    for (int i = 0; i < 4; ++i) {
        ca[i] = xbt[r0 + i][0];
        cb[i] = xbt[r0 + i][1];
    }

#pragma unroll
    for (int iw = 0; iw < W_; ++iw) {
#pragma unroll
        for (int i = 0; i < 4; ++i) cc_[i] = xbt[r0 + i][iw + 2];
        int pop0 = 0, pop1 = 0;
#pragma unroll
        for (int r = 0; r < 3; ++r) {
            // column 0 (window col iw): tap (r,0)
            uint4 wr0 = wv[r * 3 + 0], wr1 = wv[r * 3 + 1], wr2 = wv[r * 3 + 2];
            uint4 xa;
            xa = ca[r];
            pop0 += __popc(xa.x ^ wr0.x) + __popc(xa.y ^ wr0.y)
                  + __popc(xa.z ^ wr0.z) + __popc(xa.w ^ wr0.w);
            xa = ca[r + 1];
            pop1 += __popc(xa.x ^ wr0.x) + __popc(xa.y ^ wr0.y)
                  + __popc(xa.z ^ wr0.z) + __popc(xa.w ^ wr0.w);
            xa = cb[r];
            pop0 += __popc(xa.x ^ wr1.x) + __popc(xa.y ^ wr1.y)
                  + __popc(xa.z ^ wr1.z) + __popc(xa.w ^ wr1.w);
            xa = cb[r + 1];
            pop1 += __popc(xa.x ^ wr1.x) + __popc(xa.y ^ wr1.y)
                  + __popc(xa.z ^ wr1.z) + __popc(xa.w ^ wr1.w);
            xa = cc_[r];
            pop0 += __popc(xa.x ^ wr2.x) + __popc(xa.y ^ wr2.y)
                  + __popc(xa.z ^ wr2.z) + __popc(xa.w ^ wr2.w);
            xa = cc_[r + 1];
            pop1 += __popc(xa.x ^ wr2.x) + __popc(xa.y ^ wr2.y)
                  + __popc(xa.z ^ wr2.z) + __popc(xa.w ^ wr2.w);
        }
        op0[(long)iw * COUT_] = (float)(KK_ - 2 * pop0);
        op1[(long)iw * COUT_] = (float)(KK_ - 2 * pop1);
#pragma unroll
        for (int i = 0; i < 4; ++i) { ca[i] = cb[i]; cb[i] = cc_[i]; }
    }
}

// ---------------------------------------------------------------------------
extern "C" void kernel_launch(void* const* d_in, const int* in_sizes, int n_in,
                              void* d_out, int out_size, void* d_ws, size_t ws_size,
                              hipStream_t stream) {
    const int*   x   = (const int*)d_in[0];    // bool -> int32 0/1 (verified R1)
    const float* w   = (const float*)d_in[1];  // float32 0/1
    float*       out = (float*)d_out;

    // Workspace: xb (65536 uint4 = 1 MB) | wb (73728 uint4 = 1.125 MB)
    uint4*    xb  = (uint4*)d_ws;
    unsigned* wbw = (unsigned*)(xb + (D_ * H_ * W_));

    pack_kernel<<<XBLOCKS + WBLOCKS, 256, 0, stream>>>(x, w, xb, wbw);
    // conv: 64 d * 8 four-row tiles = 512 blocks (2/CU), 2 rows/thread
    binconv_kernel<<<512, 256, 0, stream>>>(xb, (const uint4*)wbw, out);
}